// Round 4
// baseline (321.091 us; speedup 1.0000x reference)
//
#include <hip/hip_runtime.h>
#include <cstddef>

// BoardModel: B=16384. out = [xf(32), a_mean(32), b2(32)] per sample, then board (3,22,12).
// MHA is degenerate (kv len 1 -> softmax==1): a_mean = out_proj(in_proj[64:96] @ b2 + b).
//
// R12 = R11 + structurally-wide LDS access (the compiler cannot narrow b128 ops):
//   - P1 stored position-major P1T[p*8 + o] (16B-aligned rows, pad 2). conv2 reads
//     each kr-window as 10 x ds_read_b128 (40 contiguous floats) -> 50 wide loads
//     replace ~174 scalar ds_read_b32 (batched waits instead of per-element).
//     conv1 writes P1 as b128+b64.  Weights stay wave-uniform -> SGPR.
//   - pcs LDS slot eliminated: piece entries packed into 1 int, broadcast by 4 __shfl;
//     sparse-tap guards become wave-uniform (SGPR-izable).
//   - LDS repack keeps 8 blocks/CU: P1T overlays SBE (all SBE reads precede P1 writes
//     in wave program order), V overlays dead C3, bmi lives in the dead C2 slot.
//     Slab = 824 floats (mod 32 = 24 -> sample slabs decorrelate across banks).
//     Total 20144 B <= 20480.
//   - Kept from R9-R11: LDS-only barriers (no vmcnt drain), ballot piece pick,
//     bitmask board channels, transposed w1L, int2 content loads, float4 tail.

#define BATCH 16384
#define SPB   4
#define NBLK  (BATCH / SPB)
#define RS    18
#define SS2    824          // floats per sample slab; 824*4 B, %16 == 0, %32(words) = 24
#define C2OFF  480          // C2 16x12 (bmi 44 ints overlay here during Phase A)
#define P2OFF  672          // P2 48
#define C3OFF  720          // C3 64
#define B2OFF  784          // B2 32
#define VOFF   720          // V 32 overlays dead C3 after lfc1
                            // [0..480): SBE 24x18=432 (Phase A/conv1) then P1T 60*8=480

// LDS-only block barrier: do NOT drain vmcnt (global stores keep flowing).
#define BSYNC() asm volatile("s_waitcnt lgkmcnt(0)\ns_barrier" ::: "memory")

// compile-time component select from a float4 array (idx must fold to a constant)
#define AF(A, i) ((i & 3) == 0 ? A[(i) >> 2].x : (i & 3) == 1 ? A[(i) >> 2].y \
                : (i & 3) == 2 ? A[(i) >> 2].z : A[(i) >> 2].w)

static __device__ __forceinline__ float dot4(float4 a, float4 b) {
  return a.x * b.x + a.y * b.y + a.z * b.z + a.w * b.w;
}

// ---- C_border precompute: cb[p*6+o] = sum over window taps hitting border-one cells,
//      summed over all 3 input channels (border is 1.0 in every channel). ----
__global__ __launch_bounds__(256)
void cborder_kernel(const float* __restrict__ w1, float* __restrict__ cb)
{
  int i = blockIdx.x * 256 + threadIdx.x;
  if (i >= 1584) return;
  int p = i / 6, o = i - p * 6;
  int y0 = p / 12, x0 = p - y0 * 12;
  float acc = 0.f;
#pragma unroll
  for (int dy = 0; dy < 5; ++dy)
#pragma unroll
    for (int dx = 0; dx < 5; ++dx) {
      int pr = y0 + dy - 2, pc = x0 + dx - 2;
      if (pr >= 0 && pr < 22 && pc >= 0 && pc < 12 &&
          (pr == 21 || pc == 0 || pc == 11)) {
        int k = dy * 5 + dx;
        acc += w1[(o * 3 + 0) * 25 + k] + w1[(o * 3 + 1) * 25 + k]
             + w1[(o * 3 + 2) * 25 + k];
      }
    }
  cb[p * 6 + o] = acc;
}

__global__ __launch_bounds__(256, 4)
void board_model_kernel(const int* __restrict__ t,           // (B,232)
                        const int* __restrict__ piece_table, // (8,4,4,4)
                        const float* __restrict__ w1, const float* __restrict__ b1,
                        const float* __restrict__ w2, const float* __restrict__ b2w,
                        const float* __restrict__ w3, const float* __restrict__ b3,
                        const float* __restrict__ wf1, const float* __restrict__ bf1,
                        const float* __restrict__ fcw, const float* __restrict__ fcb,
                        const float* __restrict__ ipw, const float* __restrict__ ipb,
                        const float* __restrict__ opw, const float* __restrict__ opb,
                        const float* __restrict__ cbg,        // (264,6) border contrib
                        float* __restrict__ out,              // (B,96)
                        float* __restrict__ out_board)        // (B,3,22,12)
{
  __shared__ __align__(16) float scr[SPB * SS2];
  __shared__ float w1L[300];     // ch1/ch2 taps, transposed: [(chm*25 + tap)*6 + o]
  __shared__ float cbL[1440];    // conv cells rows 0..19 only (cb[p*6+o], p<240)

  const int tid  = threadIdx.x;
  const int lane = tid & 63;
  const int wv   = tid >> 6;          // wave id == sample slot
  const int bb   = blockIdx.x * SPB;

  for (int i = tid; i < 300; i += 256) {
    int o = i % 6, tt = i / 6, m = tt / 25, tp = tt - m * 25;
    w1L[i] = w1[(o * 3 + m + 1) * 25 + tp];
  }
  for (int i = tid; i < 1440; i += 256) cbL[i] = cbg[i];

  int packed = 0;    // piece-entry pack, valid in lanes 0..3 after Phase A

  // ---------------- Phase A: per-wave board build + board output ----------------
  {
    float* W = &scr[wv * SS2];
    int*   bmi = (int*)&scr[wv * SS2 + C2OFF];   // 44 ints: piece row bitmasks (Phase A only)
    const int* tr = t + (size_t)(bb + wv) * 232;

    float4* W4 = (float4*)W;
    for (int i = lane; i < 108; i += 64) W4[i] = float4{0.f, 0.f, 0.f, 0.f};
    if (lane < 44) bmi[lane] = 0;

    // content only (border handled via C_border): (r, b+1) -> SBE row r+2, col b+5
    // 210 ints at tr+22 (8B aligned); even pair offsets never cross a 10-wide row.
    {
      const int2* cp = (const int2*)(tr + 22);
      for (int v = lane; v < 105; v += 64) {
        int2 cv = cp[v];
        int i0 = v * 2;
        int r = i0 / 10, b = i0 - r * 10;
        W[(r + 2) * RS + b + 5] = (float)cv.x;
        W[(r + 2) * RS + b + 6] = (float)cv.y;
      }
    }

    // piece cells -> packed entries (lane e<4: cell e; ch1 uses y, ch2 uses ny)
    // Every selected piece (t[:,8] in [0,7)) has exactly 4 set cells -> ballot+ctz.
    {
      const int* pt = piece_table + (tr[8] * 4 + tr[4]) * 16;
      int ptv = (lane < 16) ? pt[lane] : 0;
      unsigned long long bal = __ballot(ptv != 0);
      if (lane < 4) {
        unsigned x = (unsigned)bal & 0xffffu;
        for (int k = 0; k < lane; ++k) x &= x - 1;   // clear `lane` lowest set bits
        int sel = __builtin_ctz(x);
        int cy = sel >> 2, cx = sel & 3;
        int xx = cx + tr[1] - 2;
        int y  = cy + tr[2];
        int ny = y + tr[3];
        bool mask = (y >= 0) && (ny >= 0);
        bool xok  = (xx >= 0) && (xx < 10);
        bool v1 = mask && xok && (y < 21);
        bool v2 = mask && xok && (ny < 21);
        packed = (v1 ? (y & 31) : 31) | ((v2 ? (ny & 31) : 31) << 5)
               | (((xx + 2) & 15) << 10);
        if (v1) atomicOr(&bmi[y],       1 << (xx + 1));
        if (v2) atomicOr(&bmi[22 + ny], 1 << (xx + 1));
      }
    }
    __builtin_amdgcn_wave_barrier();

    // board output: ch0 = border|content from SBE; ch1/2 = border | row bitmask
    float* ob = out_board + (size_t)(bb + wv) * 792;
    for (int v = lane; v < 198; v += 64) {
      int ch = v / 66, w = v - ch * 66;      // 66 float4 per channel
      int r = w / 3, c = (w - r * 3) * 4;    // c in {0,4,8}
      float val[4];
      if (ch == 0) {
#pragma unroll
        for (int d = 0; d < 4; ++d) {
          int cd = c + d;
          val[d] = (r == 21 || cd == 0 || cd == 11) ? 1.f
                 : W[(r + 2) * RS + cd + 4];
        }
      } else {
        int bits = bmi[(ch - 1) * 22 + r];
#pragma unroll
        for (int d = 0; d < 4; ++d) {
          int cd = c + d;
          val[d] = (r == 21 || cd == 0 || cd == 11 || ((bits >> cd) & 1)) ? 1.f : 0.f;
        }
      }
      *(float4*)(ob + v * 4) = float4{val[0], val[1], val[2], val[3]};
    }
  }
  BSYNC();   // guards w1L/cbL readiness (LDS only; board stores keep draining)

  // broadcast piece entries to all lanes (registers, no LDS round-trip)
  int prA[8], pcA[8];
#pragma unroll
  for (int e = 0; e < 4; ++e) {
    int pk = __shfl(packed, e, 64);
    int r1 = pk & 31, r2 = (pk >> 5) & 31, pcc = ((pk >> 10) & 15) - 1;
    prA[e]     = (r1 == 31) ? -100 : r1;
    pcA[e]     = pcc;
    prA[e + 4] = (r2 == 31) ? -100 : r2;
    pcA[e + 4] = pcc;
  }

  // ------- Phase B: fused conv1+relu+pool1; wave = sample, lane = position <60 -------
  if (lane < 60) {
    int p = lane;
    int r = p / 6, c = p - r * 6;
    float* Wq = &scr[wv * SS2];

    // stage the full 6x6 input window (18 x ds_read_b64)
    float rw[6][6];
    {
      const float* base = Wq + (2 * r) * RS + (2 * c + 2);
#pragma unroll
      for (int u = 0; u < 6; ++u) {
        float2 a0 = *(const float2*)(base + u * RS);
        float2 a1 = *(const float2*)(base + u * RS + 2);
        float2 a2 = *(const float2*)(base + u * RS + 4);
        rw[u][0] = a0.x; rw[u][1] = a0.y; rw[u][2] = a1.x;
        rw[u][3] = a1.y; rw[u][4] = a2.x; rw[u][5] = a2.y;
      }
    }

    float acc[2][2][6];
#pragma unroll
    for (int i = 0; i < 2; ++i)
#pragma unroll
      for (int j = 0; j < 2; ++j) {
        int pcell = (2 * r + i) * 12 + (2 * c + j);
#pragma unroll
        for (int o = 0; o < 6; ++o)
          acc[i][j][o] = b1[o] + cbL[pcell * 6 + o];
      }

    // dense ch0 (600 FMA); weights via GLOBAL uniform index -> SGPR
#pragma unroll
    for (int u = 0; u < 6; ++u) {
#pragma unroll
      for (int i = 0; i < 2; ++i) {
        if (u - i < 0 || u - i > 4) continue;   // folds at compile time
        const int ky = u - i;
#pragma unroll
        for (int j = 0; j < 2; ++j)
#pragma unroll
          for (int kx = 0; kx < 5; ++kx) {
            float xv = rw[u][j + kx];
#pragma unroll
            for (int o = 0; o < 6; ++o)
              acc[i][j][o] += xv * w1[o * 75 + ky * 5 + kx];   // uniform -> SGPR
          }
      }
    }

    // sparse piece taps (value==1 -> add weight); prA wave-uniform -> cheap guards
#pragma unroll
    for (int e = 0; e < 8; ++e) {
      int pr = prA[e];
      if (pr < 0) continue;
      int pc = pcA[e];
      int chm = e >> 2;                       // 0 -> ch1, 1 -> ch2
      int dyb = pr + 2 - 2 * r;
      int dxb = pc + 2 - 2 * c;
      if (dyb < 0 || dyb > 5 || dxb < 0 || dxb > 5) continue;
#pragma unroll
      for (int i = 0; i < 2; ++i) {
        int dy = dyb - i;
        if ((unsigned)dy >= 5u) continue;
#pragma unroll
        for (int j = 0; j < 2; ++j) {
          int dx = dxb - j;
          if ((unsigned)dx >= 5u) continue;
          const float* wp = &w1L[(chm * 25 + dy * 5 + dx) * 6];
#pragma unroll
          for (int o = 0; o < 6; ++o)
            acc[i][j][o] += wp[o];
        }
      }
    }

    // P1T write: position-major [p*8 + o], overlays SBE (all SBE reads precede
    // these writes in wave program order; compiler sees the aliasing via scr).
    float v[6];
#pragma unroll
    for (int o = 0; o < 6; ++o)
      v[o] = 0.25f * (fmaxf(acc[0][0][o], 0.f) + fmaxf(acc[0][1][o], 0.f)
                    + fmaxf(acc[1][0][o], 0.f) + fmaxf(acc[1][1][o], 0.f));
    *(float4*)(Wq + p * 8)     = float4{v[0], v[1], v[2], v[3]};
    *(float2*)(Wq + p * 8 + 4) = float2{v[4], v[5]};
  }
  BSYNC();   // P1T ready across waves (LDS only)

  // ---------------- conv2+relu: wave wvu -> out-channels [4wvu,4wvu+4), all samples ----
  const int wvu = __builtin_amdgcn_readfirstlane(wv);

  if (lane < 48) {
    int q = lane / 12, p = lane - q * 12;
    int r = p >> 1, c = p & 1;
    const float* P1q = &scr[q * SS2];
    float a4[4];
#pragma unroll
    for (int oo = 0; oo < 4; ++oo) a4[oo] = b2w[4 * wvu + oo];
#pragma unroll
    for (int kr = 0; kr < 5; ++kr) {
      // window row: 5 consecutive positions * 8 floats = 40 contiguous, 16B aligned
      const float4* pp = (const float4*)(P1q + ((r + kr) * 6 + c) * 8);
      float4 A[10];
#pragma unroll
      for (int m = 0; m < 10; ++m) A[m] = pp[m];
#pragma unroll
      for (int kc = 0; kc < 5; ++kc)
#pragma unroll
        for (int ic = 0; ic < 6; ++ic) {
          const int idx = kc * 8 + ic;
          float xv = AF(A, idx);
#pragma unroll
          for (int oo = 0; oo < 4; ++oo)
            a4[oo] += xv * w2[(((4 * wvu + oo) * 6 + ic) * 5 + kr) * 5 + kc];
        }
    }
    float* C2q = &scr[q * SS2 + C2OFF];
#pragma unroll
    for (int oo = 0; oo < 4; ++oo)
      C2q[(4 * wvu + oo) * 12 + p] = fmaxf(a4[oo], 0.f);
  }
  BSYNC();   // C2 ready (LDS only)

  // ---------------- per-wave tail: wave q owns sample q ----------------
  {
    const int q = wvu;
    float* S = &scr[q * SS2];

    // pool2: one b128 per lane
    if (lane < 48) {
      int o = lane / 3, pr = lane - o * 3;
      float4 v4 = *(const float4*)(S + C2OFF + o * 12 + 4 * pr);
      S[P2OFF + lane] = 0.25f * (v4.x + v4.y + v4.z + v4.w);
    }
    __builtin_amdgcn_wave_barrier();

    // conv3 (fc over 48): per-lane row of w3 as 12 float4
    {
      int o = lane;
      const float4* w34 = (const float4*)(w3 + o * 48);
      const float4* S4  = (const float4*)(S + P2OFF);
      float acc = b3[o];
#pragma unroll
      for (int m = 0; m < 12; ++m)
        acc += dot4(S4[m], w34[m]);
      S[C3OFF + o] = fmaxf(acc, 0.f);
    }
    __builtin_amdgcn_wave_barrier();

    // lfc1: rows of wf1 as float4; split-k halves combined via shfl
    {
      int j = lane & 31, h = lane >> 5;
      const float4* wf4 = (const float4*)(wf1 + j * 64 + 32 * h);
      const float4* S4  = (const float4*)(S + C3OFF + 32 * h);
      float part = 0.f;
#pragma unroll
      for (int m = 0; m < 8; ++m)
        part += dot4(S4[m], wf4[m]);
      part += __shfl_xor(part, 32, 64);
      if (h == 0) {
        float acc = fmaxf(bf1[j] + part, 0.f);
        S[B2OFF + j] = acc;
        out[(size_t)(bb + q) * 96 + 64 + j] = acc;
      }
    }
    __builtin_amdgcn_wave_barrier();

    {
      int j = lane & 31;
      if (lane < 32) {
        // v-proj: rows 64..95 of ipw as float4; V overlays dead C3
        const float4* ip4 = (const float4*)(ipw + (size_t)(64 + j) * 32);
        const float4* S4  = (const float4*)(S + B2OFF);
        float acc = ipb[64 + j];
#pragma unroll
        for (int m = 0; m < 8; ++m)
          acc += dot4(S4[m], ip4[m]);
        S[VOFF + j] = acc;
      } else {
        // xf: t row is 928B (16B aligned); fcw row is 32B
        const int4* t4 = (const int4*)(t + (size_t)(bb + q) * 232);
        int4 ta = t4[0], tb = t4[1];
        const float4* fc4 = (const float4*)(fcw + j * 8);
        float4 wa = fc4[0], wb = fc4[1];
        float acc = fcb[j]
                  + (float)ta.x * wa.x + (float)ta.y * wa.y
                  + (float)ta.z * wa.z + (float)ta.w * wa.w
                  + (float)tb.x * wb.x + (float)tb.y * wb.y
                  + (float)tb.z * wb.z + (float)tb.w * wb.w;
        out[(size_t)(bb + q) * 96 + j] = fmaxf(acc, 0.f);
      }
    }
    __builtin_amdgcn_wave_barrier();

    if (lane < 32) {
      int j = lane;
      const float4* op4 = (const float4*)(opw + j * 32);
      const float4* S4  = (const float4*)(S + VOFF);
      float acc = opb[j];
#pragma unroll
      for (int m = 0; m < 8; ++m)
        acc += dot4(S4[m], op4[m]);
      out[(size_t)(bb + q) * 96 + 32 + j] = acc;
    }
  }
}

extern "C" void kernel_launch(void* const* d_in, const int* in_sizes, int n_in,
                              void* d_out, int out_size, void* d_ws, size_t ws_size,
                              hipStream_t stream) {
  const int*   t   = (const int*)d_in[0];
  const int*   pt  = (const int*)d_in[1];
  const float* w1  = (const float*)d_in[2];
  const float* b1  = (const float*)d_in[3];
  const float* w2  = (const float*)d_in[4];
  const float* b2w = (const float*)d_in[5];
  const float* w3  = (const float*)d_in[6];
  const float* b3  = (const float*)d_in[7];
  const float* wf1 = (const float*)d_in[8];
  const float* bf1 = (const float*)d_in[9];
  const float* fcw = (const float*)d_in[10];
  const float* fcb = (const float*)d_in[11];
  // d_in[12] = emb : dead (softmax over singleton axis == 1)
  const float* ipw = (const float*)d_in[13];
  const float* ipb = (const float*)d_in[14];
  const float* opw = (const float*)d_in[15];
  const float* opb = (const float*)d_in[16];

  float* out       = (float*)d_out;
  float* out_board = out + (size_t)BATCH * 96;
  float* cbg       = (float*)d_ws;     // 1584 floats

  hipLaunchKernelGGL(cborder_kernel, dim3(7), dim3(256), 0, stream, w1, cbg);
  hipLaunchKernelGGL(board_model_kernel, dim3(NBLK), dim3(256), 0, stream,
                     t, pt, w1, b1, w2, b2w, w3, b3, wf1, bf1, fcw, fcb,
                     ipw, ipb, opw, opb, cbg, out, out_board);
}

// Round 5
// 261.914 us; speedup vs baseline: 1.2259x; 1.2259x over previous
//
#include <hip/hip_runtime.h>
#include <cstddef>

// BoardModel: B=16384. out = [xf(32), a_mean(32), b2(32)] per sample, then board (3,22,12).
// MHA is degenerate (kv len 1 -> softmax==1): a_mean = out_proj(in_proj[64:96] @ b2 + b).
//
// R13 = R11 (revert of R12) + weight path moved off SMEM/lgkmcnt:
//   - R12 post-mortem: position-major P1 + select expansion ~3x'd VALU work -> 226us.
//     Full revert to R11 structure (P1 stride 61, pcs in LDS, scalar vals staging).
//   - NEW: conv1-dense and conv2 weights were wave-uniform -> s_load (SMEM).
//     SMEM shares lgkmcnt with LDS: with 112 SGPRs the 600-float w2 block issues as
//     {s_load batch -> lgkmcnt wait -> FMAs -> ...}, each wait also draining the
//     outstanding LDS input reads. That serialization is why R10/R11's VGPR-side
//     batching was null (VGPR stuck at 40: the schedule never needed width).
//     Fix: prep kernel repacks w1-ch0 -> w1T[tap*8+o], w2 -> w2T[tap*16+o] in d_ws;
//     conv loops load weights as per-lane VMEM float4 with divergent-valued index
//     (wv, and dz = wv - readfirstlane(wv)) -> global_load_dwordx4, one L1-broadcast
//     per tap, waits on vmcnt (decoupled from LDS).  w1T=200B, w2T=9.6KB: L1-resident.
//   - Kept from R9-R11: LDS-only barriers (no vmcnt drain), ballot piece pick,
//     bitmask board channels, transposed w1L (sparse taps), int2 content loads,
//     float4 tail weight loads.

#define BATCH 16384
#define SPB   4
#define NBLK  (BATCH / SPB)
#define RS    18
#define SBE_SZ 432          // 24 rows x 18
#define P1OFF  432          // P1: [o*61 + p], p<60 -> 366 floats (bmi overlays this in Phase A)
#define PCSOFF 800          // 16 ints
#define SS2    816          // floats per sample; 816*4 % 16 == 0
                            // tail overlays SBE: C2 192 @0, P2 48 @192, C3 64 @240,
                            // B2 32 @304, V 32 @336.

// workspace float offsets
#define WS_CB   0           // 1584: border contribs
#define WS_W1T  1600        // 200:  w1T[tap*8 + o], o<6 (ch0 dense taps)
#define WS_W2T  1800        // 2400: w2T[tap*16 + o]
#define WS_TOT  4200

// LDS-only block barrier: do NOT drain vmcnt (global stores keep flowing).
#define BSYNC() asm volatile("s_waitcnt lgkmcnt(0)\ns_barrier" ::: "memory")

static __device__ __forceinline__ float dot4(float4 a, float4 b) {
  return a.x * b.x + a.y * b.y + a.z * b.z + a.w * b.w;
}

// ---- prep: C_border + weight repacks ----
__global__ __launch_bounds__(256)
void prep_kernel(const float* __restrict__ w1, const float* __restrict__ w2,
                 float* __restrict__ ws)
{
  int i = blockIdx.x * 256 + threadIdx.x;
  if (i < 1584) {
    int p = i / 6, o = i - p * 6;
    int y0 = p / 12, x0 = p - y0 * 12;
    float acc = 0.f;
#pragma unroll
    for (int dy = 0; dy < 5; ++dy)
#pragma unroll
      for (int dx = 0; dx < 5; ++dx) {
        int pr = y0 + dy - 2, pc = x0 + dx - 2;
        if (pr >= 0 && pr < 22 && pc >= 0 && pc < 12 &&
            (pr == 21 || pc == 0 || pc == 11)) {
          int k = dy * 5 + dx;
          acc += w1[(o * 3 + 0) * 25 + k] + w1[(o * 3 + 1) * 25 + k]
               + w1[(o * 3 + 2) * 25 + k];
        }
      }
    ws[WS_CB + p * 6 + o] = acc;
  } else if (i < 1784) {
    int idx = i - 1584;                 // w1T[tap*8 + o] = w1[o*75 + tap] (ch0)
    int tap = idx >> 3, o = idx & 7;
    ws[WS_W1T + idx] = (o < 6) ? w1[o * 75 + tap] : 0.f;
  } else if (i < WS_TOT) {
    int idx = i - 1784;                 // w2T[tap*16 + o] = w2[o*150 + tap]
    int tap = idx >> 4, o = idx & 15;
    ws[WS_W2T + idx] = w2[o * 150 + tap];
  }
}

__global__ __launch_bounds__(256, 4)
void board_model_kernel(const int* __restrict__ t,           // (B,232)
                        const int* __restrict__ piece_table, // (8,4,4,4)
                        const float* __restrict__ w1, const float* __restrict__ b1,
                        const float* __restrict__ w2, const float* __restrict__ b2w,
                        const float* __restrict__ w3, const float* __restrict__ b3,
                        const float* __restrict__ wf1, const float* __restrict__ bf1,
                        const float* __restrict__ fcw, const float* __restrict__ fcb,
                        const float* __restrict__ ipw, const float* __restrict__ ipb,
                        const float* __restrict__ opw, const float* __restrict__ opb,
                        const float* __restrict__ cbg,        // workspace (see WS_*)
                        float* __restrict__ out,              // (B,96)
                        float* __restrict__ out_board)        // (B,3,22,12)
{
  __shared__ __align__(16) float scr[SPB * SS2];
  __shared__ float w1L[300];     // ch1/ch2 taps, transposed: [(chm*25 + tap)*6 + o]
  __shared__ float cbL[1440];    // conv cells rows 0..19 only (cb[p*6+o], p<240)

  const int tid  = threadIdx.x;
  const int lane = tid & 63;
  const int wv   = tid >> 6;          // wave id == sample slot
  const int bb   = blockIdx.x * SPB;

  for (int i = tid; i < 300; i += 256) {
    int o = i % 6, tt = i / 6, m = tt / 25, tp = tt - m * 25;
    w1L[i] = w1[(o * 3 + m + 1) * 25 + tp];
  }
  for (int i = tid; i < 1440; i += 256) cbL[i] = cbg[i];

  // ---------------- Phase A: per-wave board build + board output ----------------
  {
    float* W = &scr[wv * SS2];
    int*   pcs = (int*)&scr[wv * SS2 + PCSOFF];
    int*   bmi = (int*)&scr[wv * SS2 + P1OFF];   // 44 ints: piece row bitmasks (Phase A only)
    const int* tr = t + (size_t)(bb + wv) * 232;

    float4* W4 = (float4*)W;
    for (int i = lane; i < 108; i += 64) W4[i] = float4{0.f, 0.f, 0.f, 0.f};
    if (lane < 44) bmi[lane] = 0;

    // content only (border handled via C_border): (r, b+1) -> SBE row r+2, col b+5
    // 210 ints at tr+22 (8B aligned); even pair offsets never cross a 10-wide row.
    {
      const int2* cp = (const int2*)(tr + 22);
      for (int v = lane; v < 105; v += 64) {
        int2 cv = cp[v];
        int i0 = v * 2;
        int r = i0 / 10, b = i0 - r * 10;
        W[(r + 2) * RS + b + 5] = (float)cv.x;
        W[(r + 2) * RS + b + 6] = (float)cv.y;
      }
    }

    // piece cells -> entry list (8 entries: e<4 ch1 uses y, e>=4 ch2 uses ny)
    // Every selected piece (t[:,8] in [0,7)) has exactly 4 set cells -> ballot+ctz.
    {
      const int* pt = piece_table + (tr[8] * 4 + tr[4]) * 16;
      int ptv = (lane < 16) ? pt[lane] : 0;
      unsigned long long bal = __ballot(ptv != 0);
      if (lane < 4) {
        unsigned x = (unsigned)bal & 0xffffu;
        for (int k = 0; k < lane; ++k) x &= x - 1;   // clear `lane` lowest set bits
        int sel = __builtin_ctz(x);
        int cy = sel >> 2, cx = sel & 3;
        int xx = cx + tr[1] - 2;
        int y  = cy + tr[2];
        int ny = y + tr[3];
        bool mask = (y >= 0) && (ny >= 0);
        bool xok  = (xx >= 0) && (xx < 10);
        bool v1 = mask && xok && (y < 21);
        bool v2 = mask && xok && (ny < 21);
        pcs[2 * lane + 0]       = v1 ? y  : -100;   // padded-board row
        pcs[2 * lane + 1]       = xx + 1;           // padded-board col
        pcs[2 * (lane + 4)]     = v2 ? ny : -100;
        pcs[2 * (lane + 4) + 1] = xx + 1;
        if (v1) atomicOr(&bmi[y],       1 << (xx + 1));
        if (v2) atomicOr(&bmi[22 + ny], 1 << (xx + 1));
      }
    }
    __builtin_amdgcn_wave_barrier();

    // board output: ch0 = border|content from SBE; ch1/2 = border | row bitmask
    float* ob = out_board + (size_t)(bb + wv) * 792;
    for (int v = lane; v < 198; v += 64) {
      int ch = v / 66, w = v - ch * 66;      // 66 float4 per channel
      int r = w / 3, c = (w - r * 3) * 4;    // c in {0,4,8}
      float val[4];
      if (ch == 0) {
#pragma unroll
        for (int d = 0; d < 4; ++d) {
          int cd = c + d;
          val[d] = (r == 21 || cd == 0 || cd == 11) ? 1.f
                 : W[(r + 2) * RS + cd + 4];
        }
      } else {
        int bits = bmi[(ch - 1) * 22 + r];
#pragma unroll
        for (int d = 0; d < 4; ++d) {
          int cd = c + d;
          val[d] = (r == 21 || cd == 0 || cd == 11 || ((bits >> cd) & 1)) ? 1.f : 0.f;
        }
      }
      *(float4*)(ob + v * 4) = float4{val[0], val[1], val[2], val[3]};
    }
  }
  BSYNC();   // guards w1L/cbL readiness (LDS only; board stores keep draining)

  const int wvu = __builtin_amdgcn_readfirstlane(wv);
  const int dz  = wv - wvu;      // divergent-VALUED zero: defeats uniformity analysis
                                 // so weight loads stay VMEM (vmcnt), not SMEM (lgkmcnt)

  // ------- Phase B: fused conv1+relu+pool1; wave = sample, lane = position <60 -------
  if (lane < 60) {
    int p = lane;
    int r = p / 6, c = p - r * 6;
    const float* Wq  = &scr[wv * SS2];
    const int*   pcs = (const int*)&scr[wv * SS2 + PCSOFF];

    // hoist piece entries into registers (LDS reads hide under the dense FMAs)
    int prA[8], pcA[8];
#pragma unroll
    for (int e = 0; e < 8; ++e) { prA[e] = pcs[2 * e]; pcA[e] = pcs[2 * e + 1]; }

    // stage the full 6x6 input window (18 x ds_read_b64)
    float rw[6][6];
    {
      const float* base = Wq + (2 * r) * RS + (2 * c + 2);
#pragma unroll
      for (int u = 0; u < 6; ++u) {
        float2 a0 = *(const float2*)(base + u * RS);
        float2 a1 = *(const float2*)(base + u * RS + 2);
        float2 a2 = *(const float2*)(base + u * RS + 4);
        rw[u][0] = a0.x; rw[u][1] = a0.y; rw[u][2] = a1.x;
        rw[u][3] = a1.y; rw[u][4] = a2.x; rw[u][5] = a2.y;
      }
    }

    float acc[2][2][6];
#pragma unroll
    for (int i = 0; i < 2; ++i)
#pragma unroll
      for (int j = 0; j < 2; ++j) {
        int pcell = (2 * r + i) * 12 + (2 * c + j);
#pragma unroll
        for (int o = 0; o < 6; ++o)
          acc[i][j][o] = b1[o] + cbL[pcell * 6 + o];
      }

    // dense ch0 (600 FMA); weights via per-lane VMEM float4 (L1 broadcast, vmcnt)
    {
      const float* w1T = cbg + WS_W1T + dz;
#pragma unroll
      for (int ky = 0; ky < 5; ++ky)
#pragma unroll
        for (int kx = 0; kx < 5; ++kx) {
          const float* wp = w1T + (ky * 5 + kx) * 8;
          float4 wa = *(const float4*)(wp);
          float2 wb = *(const float2*)(wp + 4);
          float wt[6] = {wa.x, wa.y, wa.z, wa.w, wb.x, wb.y};
#pragma unroll
          for (int i = 0; i < 2; ++i) {
            const int u = ky + i;               // input row
#pragma unroll
            for (int j = 0; j < 2; ++j) {
              float xv = rw[u][j + kx];
#pragma unroll
              for (int o = 0; o < 6; ++o)
                acc[i][j][o] += xv * wt[o];
            }
          }
        }
    }

    // sparse piece taps (value==1 -> add weight); divergent -> w1L (o-contiguous)
#pragma unroll
    for (int e = 0; e < 8; ++e) {
      int pr = prA[e];
      if (pr < 0) continue;
      int pc = pcA[e];
      int chm = e >> 2;                       // 0 -> ch1, 1 -> ch2
      int dyb = pr + 2 - 2 * r;
      int dxb = pc + 2 - 2 * c;
      if (dyb < 0 || dyb > 5 || dxb < 0 || dxb > 5) continue;
#pragma unroll
      for (int i = 0; i < 2; ++i) {
        int dy = dyb - i;
        if ((unsigned)dy >= 5u) continue;
#pragma unroll
        for (int j = 0; j < 2; ++j) {
          int dx = dxb - j;
          if ((unsigned)dx >= 5u) continue;
          const float* wp = &w1L[(chm * 25 + dy * 5 + dx) * 6];
#pragma unroll
          for (int o = 0; o < 6; ++o)
            acc[i][j][o] += wp[o];
        }
      }
    }

    float* P1q = &scr[wv * SS2 + P1OFF];
#pragma unroll
    for (int o = 0; o < 6; ++o) {
      float v = fmaxf(acc[0][0][o], 0.f) + fmaxf(acc[0][1][o], 0.f)
              + fmaxf(acc[1][0][o], 0.f) + fmaxf(acc[1][1][o], 0.f);
      P1q[o * 61 + p] = 0.25f * v;
    }
  }
  BSYNC();   // P1 ready across waves (LDS only)

  // ---------------- conv2+relu: wave wv -> out-channels [4wv,4wv+4), all samples ----
  if (lane < 48) {
    int q = lane / 12, p = lane - q * 12;
    int r = p >> 1, c = p & 1;
    const float* P1q = &scr[q * SS2 + P1OFF];
    float a4[4];
#pragma unroll
    for (int oo = 0; oo < 4; ++oo) a4[oo] = b2w[4 * wvu + oo];

    const float* wbase = cbg + WS_W2T + 4 * wv;   // divergent -> VMEM float4 per tap
#pragma unroll
    for (int ic = 0; ic < 6; ++ic) {
      // stage a contiguous 29-float window: covers taps kr*6+kc (kr,kc<5)
      float vals[29];
      const float* pb = P1q + ic * 61 + r * 6 + c;
#pragma unroll
      for (int m = 0; m < 29; ++m) vals[m] = pb[m];
#pragma unroll
      for (int kr = 0; kr < 5; ++kr)
#pragma unroll
        for (int kc = 0; kc < 5; ++kc) {
          float4 wt = *(const float4*)(wbase + (ic * 25 + kr * 5 + kc) * 16);
          float xv = vals[kr * 6 + kc];
          a4[0] += xv * wt.x; a4[1] += xv * wt.y;
          a4[2] += xv * wt.z; a4[3] += xv * wt.w;
        }
    }
    float* C2q = &scr[q * SS2];
#pragma unroll
    for (int oo = 0; oo < 4; ++oo)
      C2q[(4 * wvu + oo) * 12 + p] = fmaxf(a4[oo], 0.f);
  }
  BSYNC();   // C2 ready (LDS only)

  // ---------------- per-wave tail: wave q owns sample q ----------------
  {
    const int q = wvu;
    float* S = &scr[q * SS2];

    // pool2: one b128 per lane (o*12+4*pr is a multiple of 4 floats; slab 16B aligned)
    if (lane < 48) {
      int o = lane / 3, pr = lane - o * 3;
      float4 v4 = *(const float4*)(S + o * 12 + 4 * pr);
      S[192 + lane] = 0.25f * (v4.x + v4.y + v4.z + v4.w);
    }
    __builtin_amdgcn_wave_barrier();

    // conv3 (fc over 48): per-lane row of w3 as 12 float4 (row = 192B, 16B aligned)
    {
      int o = lane;
      const float4* w34 = (const float4*)(w3 + o * 48);
      const float4* S4  = (const float4*)(S + 192);
      float acc = b3[o];
#pragma unroll
      for (int m = 0; m < 12; ++m)
        acc += dot4(S4[m], w34[m]);
      S[240 + o] = fmaxf(acc, 0.f);
    }
    __builtin_amdgcn_wave_barrier();

    // lfc1: rows of wf1 (256B) as float4; split-k halves combined via shfl
    {
      int j = lane & 31, h = lane >> 5;
      const float4* wf4 = (const float4*)(wf1 + j * 64 + 32 * h);
      const float4* S4  = (const float4*)(S + 240 + 32 * h);
      float part = 0.f;
#pragma unroll
      for (int m = 0; m < 8; ++m)
        part += dot4(S4[m], wf4[m]);
      part += __shfl_xor(part, 32, 64);
      if (h == 0) {
        float acc = fmaxf(bf1[j] + part, 0.f);
        S[304 + j] = acc;
        out[(size_t)(bb + q) * 96 + 64 + j] = acc;
      }
    }
    __builtin_amdgcn_wave_barrier();

    {
      int j = lane & 31;
      if (lane < 32) {
        // v-proj: rows 64..95 of ipw (128B rows) as float4
        const float4* ip4 = (const float4*)(ipw + (size_t)(64 + j) * 32);
        const float4* S4  = (const float4*)(S + 304);
        float acc = ipb[64 + j];
#pragma unroll
        for (int m = 0; m < 8; ++m)
          acc += dot4(S4[m], ip4[m]);
        S[336 + j] = acc;
      } else {
        // xf: t row is 928B (16B aligned); fcw row is 32B
        const int4* t4 = (const int4*)(t + (size_t)(bb + q) * 232);
        int4 ta = t4[0], tb = t4[1];
        const float4* fc4 = (const float4*)(fcw + j * 8);
        float4 wa = fc4[0], wb = fc4[1];
        float acc = fcb[j]
                  + (float)ta.x * wa.x + (float)ta.y * wa.y
                  + (float)ta.z * wa.z + (float)ta.w * wa.w
                  + (float)tb.x * wb.x + (float)tb.y * wb.y
                  + (float)tb.z * wb.z + (float)tb.w * wb.w;
        out[(size_t)(bb + q) * 96 + j] = fmaxf(acc, 0.f);
      }
    }
    __builtin_amdgcn_wave_barrier();

    if (lane < 32) {
      int j = lane;
      const float4* op4 = (const float4*)(opw + j * 32);
      const float4* S4  = (const float4*)(S + 336);
      float acc = opb[j];
#pragma unroll
      for (int m = 0; m < 8; ++m)
        acc += dot4(S4[m], op4[m]);
      out[(size_t)(bb + q) * 96 + 32 + j] = acc;
    }
  }
}

extern "C" void kernel_launch(void* const* d_in, const int* in_sizes, int n_in,
                              void* d_out, int out_size, void* d_ws, size_t ws_size,
                              hipStream_t stream) {
  const int*   t   = (const int*)d_in[0];
  const int*   pt  = (const int*)d_in[1];
  const float* w1  = (const float*)d_in[2];
  const float* b1  = (const float*)d_in[3];
  const float* w2  = (const float*)d_in[4];
  const float* b2w = (const float*)d_in[5];
  const float* w3  = (const float*)d_in[6];
  const float* b3  = (const float*)d_in[7];
  const float* wf1 = (const float*)d_in[8];
  const float* bf1 = (const float*)d_in[9];
  const float* fcw = (const float*)d_in[10];
  const float* fcb = (const float*)d_in[11];
  // d_in[12] = emb : dead (softmax over singleton axis == 1)
  const float* ipw = (const float*)d_in[13];
  const float* ipb = (const float*)d_in[14];
  const float* opw = (const float*)d_in[15];
  const float* opb = (const float*)d_in[16];

  float* out       = (float*)d_out;
  float* out_board = out + (size_t)BATCH * 96;
  float* cbg       = (float*)d_ws;     // WS_TOT floats (cb + w1T + w2T)

  hipLaunchKernelGGL(prep_kernel, dim3(17), dim3(256), 0, stream, w1, w2, cbg);
  hipLaunchKernelGGL(board_model_kernel, dim3(NBLK), dim3(256), 0, stream,
                     t, pt, w1, b1, w2, b2w, w3, b3, wf1, bf1, fcw, fcb,
                     ipw, ipb, opw, opb, cbg, out, out_board);
}

// Round 6
// 207.110 us; speedup vs baseline: 1.5503x; 1.2646x over previous
//
#include <hip/hip_runtime.h>
#include <cstddef>

// BoardModel: B=16384. out = [xf(32), a_mean(32), b2(32)] per sample, then board (3,22,12).
// MHA is degenerate (kv len 1 -> softmax==1): a_mean = out_proj(in_proj[64:96] @ b2 + b).
//
// R14 = barrier-free wave-independent restructure (post R12/R13 reverts):
//   - Every wave processes ONE sample end-to-end: Phase A -> conv1 -> conv2 -> tail.
//     NO block barriers anywhere (only intra-wave wave_barrier ordering).  The 3
//     __syncthreads convoys existed only because conv2/tail were cross-wave-split
//     to keep w2 wave-uniform; R13 showed the weight path matters less than the
//     coupling.  Waves now desynchronize and hide each other's stalls.
//   - conv2 per-wave: lane = (oc-group og, position p); weights from LDS w2L
//     [tap*16+oc] (repacked by prep): one ds_read_b128 per tap at immediate
//     offset, og-spread hits banks 0/4/8/12 -> conflict-free broadcast.
//   - w1L/w2L staged per-wave REDUNDANTLY (identical values, benign LDS races)
//     so no block-level producer/consumer edge remains.
//   - cbL moved out of LDS: conv1 init reads cb8[pcell*8+o] (padded, 32B stride,
//     aligned float4+float2) straight from global -- L1-resident, 8 independent
//     loads hidden under the dense FMA stream.
//   - LDS = scr 13056 + w1L 1200 + w2L 9600 = 23856 B -> 6 blocks/CU, 24 waves/CU.
//   - Kept from R9-R11: ballot piece pick, bitmask board channels, int2 content
//     loads, SMEM (s_load) conv1 dense weights, float4 tail, stride-61 P1.

#define BATCH 16384
#define SPB   4
#define NBLK  (BATCH / SPB)
#define RS    18
#define P1OFF  432          // P1: [o*61 + p], p<60 (bmi overlays this in Phase A)
#define PCSOFF 800          // 16 ints
#define SS2    816          // floats per sample slab
                            // tail overlays SBE: C2 192 @0, P2 48 @192, C3 64 @240,
                            // B2 32 @304, V 32 @336.

// workspace float offsets
#define WS_CB   0           // 2112: cb8[pcell*8 + o], o<6 used (pad 2)
#define WS_W2T  2112        // 2400: w2T[tap*16 + oc]
#define WS_TOT  4512

static __device__ __forceinline__ float dot4(float4 a, float4 b) {
  return a.x * b.x + a.y * b.y + a.z * b.z + a.w * b.w;
}

// ---- prep: C_border (padded stride 8) + w2 transpose ----
__global__ __launch_bounds__(256)
void prep_kernel(const float* __restrict__ w1, const float* __restrict__ w2,
                 float* __restrict__ ws)
{
  int i = blockIdx.x * 256 + threadIdx.x;
  if (i < 2112) {
    int p = i >> 3, o = i & 7;
    float acc = 0.f;
    if (o < 6) {
      int y0 = p / 12, x0 = p - y0 * 12;
#pragma unroll
      for (int dy = 0; dy < 5; ++dy)
#pragma unroll
        for (int dx = 0; dx < 5; ++dx) {
          int pr = y0 + dy - 2, pc = x0 + dx - 2;
          if (pr >= 0 && pr < 22 && pc >= 0 && pc < 12 &&
              (pr == 21 || pc == 0 || pc == 11)) {
            int k = dy * 5 + dx;
            acc += w1[(o * 3 + 0) * 25 + k] + w1[(o * 3 + 1) * 25 + k]
                 + w1[(o * 3 + 2) * 25 + k];
          }
        }
    }
    ws[WS_CB + i] = acc;
  } else if (i < WS_TOT) {
    int idx = i - WS_W2T;               // w2T[tap*16 + o] = w2[o*150 + tap]
    int tap = idx >> 4, o = idx & 15;
    ws[WS_W2T + idx] = w2[o * 150 + tap];
  }
}

__global__ __launch_bounds__(256)
void board_model_kernel(const int* __restrict__ t,           // (B,232)
                        const int* __restrict__ piece_table, // (8,4,4,4)
                        const float* __restrict__ w1, const float* __restrict__ b1,
                        const float* __restrict__ w2, const float* __restrict__ b2w,
                        const float* __restrict__ w3, const float* __restrict__ b3,
                        const float* __restrict__ wf1, const float* __restrict__ bf1,
                        const float* __restrict__ fcw, const float* __restrict__ fcb,
                        const float* __restrict__ ipw, const float* __restrict__ ipb,
                        const float* __restrict__ opw, const float* __restrict__ opb,
                        const float* __restrict__ cbg,        // workspace (see WS_*)
                        float* __restrict__ out,              // (B,96)
                        float* __restrict__ out_board)        // (B,3,22,12)
{
  __shared__ __align__(16) float scr[SPB * SS2];
  __shared__ __align__(16) float w1L[300];    // ch1/ch2 taps: [(chm*25+tap)*6 + o]
  __shared__ __align__(16) float w2L[2400];   // [tap*16 + oc]

  const int tid  = threadIdx.x;
  const int lane = tid & 63;
  const int wv   = tid >> 6;          // wave id == sample slot
  const int bb   = blockIdx.x * SPB;

  // per-wave REDUNDANT staging (each wave writes the full arrays with identical
  // values -> it only ever depends on its OWN writes; no block barrier needed).
  for (int i = lane; i < 300; i += 64) {
    int o = i % 6, tt = i / 6, m = tt / 25, tp = tt - m * 25;
    w1L[i] = w1[(o * 3 + m + 1) * 25 + tp];
  }
  {
    const float4* src = (const float4*)(cbg + WS_W2T);
    float4* dst = (float4*)w2L;
    for (int i = lane; i < 600; i += 64) dst[i] = src[i];
  }

  // ---------------- Phase A: per-wave board build + board output ----------------
  {
    float* W = &scr[wv * SS2];
    int*   pcs = (int*)&scr[wv * SS2 + PCSOFF];
    int*   bmi = (int*)&scr[wv * SS2 + P1OFF];   // 44 ints (Phase A only)
    const int* tr = t + (size_t)(bb + wv) * 232;

    float4* W4 = (float4*)W;
    for (int i = lane; i < 108; i += 64) W4[i] = float4{0.f, 0.f, 0.f, 0.f};
    if (lane < 44) bmi[lane] = 0;

    // content: (r, b+1) -> SBE row r+2, col b+5; 210 ints at tr+22 (8B aligned)
    {
      const int2* cp = (const int2*)(tr + 22);
      for (int v = lane; v < 105; v += 64) {
        int2 cv = cp[v];
        int i0 = v * 2;
        int r = i0 / 10, b = i0 - r * 10;
        W[(r + 2) * RS + b + 5] = (float)cv.x;
        W[(r + 2) * RS + b + 6] = (float)cv.y;
      }
    }

    // piece cells -> entry list; pieces always have exactly 4 cells -> ballot+ctz
    {
      const int* pt = piece_table + (tr[8] * 4 + tr[4]) * 16;
      int ptv = (lane < 16) ? pt[lane] : 0;
      unsigned long long bal = __ballot(ptv != 0);
      if (lane < 4) {
        unsigned x = (unsigned)bal & 0xffffu;
        for (int k = 0; k < lane; ++k) x &= x - 1;   // clear `lane` lowest set bits
        int sel = __builtin_ctz(x);
        int cy = sel >> 2, cx = sel & 3;
        int xx = cx + tr[1] - 2;
        int y  = cy + tr[2];
        int ny = y + tr[3];
        bool mask = (y >= 0) && (ny >= 0);
        bool xok  = (xx >= 0) && (xx < 10);
        bool v1 = mask && xok && (y < 21);
        bool v2 = mask && xok && (ny < 21);
        pcs[2 * lane + 0]       = v1 ? y  : -100;   // padded-board row
        pcs[2 * lane + 1]       = xx + 1;           // padded-board col
        pcs[2 * (lane + 4)]     = v2 ? ny : -100;
        pcs[2 * (lane + 4) + 1] = xx + 1;
        if (v1) atomicOr(&bmi[y],       1 << (xx + 1));
        if (v2) atomicOr(&bmi[22 + ny], 1 << (xx + 1));
      }
    }
    __builtin_amdgcn_wave_barrier();

    // board output: ch0 = border|content from SBE; ch1/2 = border | row bitmask
    float* ob = out_board + (size_t)(bb + wv) * 792;
    for (int v = lane; v < 198; v += 64) {
      int ch = v / 66, w = v - ch * 66;      // 66 float4 per channel
      int r = w / 3, c = (w - r * 3) * 4;    // c in {0,4,8}
      float val[4];
      if (ch == 0) {
#pragma unroll
        for (int d = 0; d < 4; ++d) {
          int cd = c + d;
          val[d] = (r == 21 || cd == 0 || cd == 11) ? 1.f
                 : W[(r + 2) * RS + cd + 4];
        }
      } else {
        int bits = bmi[(ch - 1) * 22 + r];
#pragma unroll
        for (int d = 0; d < 4; ++d) {
          int cd = c + d;
          val[d] = (r == 21 || cd == 0 || cd == 11 || ((bits >> cd) & 1)) ? 1.f : 0.f;
        }
      }
      *(float4*)(ob + v * 4) = float4{val[0], val[1], val[2], val[3]};
    }
  }
  __builtin_amdgcn_wave_barrier();

  const int wvu = __builtin_amdgcn_readfirstlane(wv);

  // ------- conv1+relu+pool1 (own sample); lane = pool position <60 -------
  if (lane < 60) {
    int p = lane;
    int r = p / 6, c = p - r * 6;
    const float* Wq  = &scr[wv * SS2];
    const int*   pcs = (const int*)&scr[wv * SS2 + PCSOFF];

    // hoist piece entries into registers
    int prA[8], pcA[8];
#pragma unroll
    for (int e = 0; e < 8; ++e) { prA[e] = pcs[2 * e]; pcA[e] = pcs[2 * e + 1]; }

    // stage the full 6x6 input window (18 x ds_read_b64)
    float rw[6][6];
    {
      const float* base = Wq + (2 * r) * RS + (2 * c + 2);
#pragma unroll
      for (int u = 0; u < 6; ++u) {
        float2 a0 = *(const float2*)(base + u * RS);
        float2 a1 = *(const float2*)(base + u * RS + 2);
        float2 a2 = *(const float2*)(base + u * RS + 4);
        rw[u][0] = a0.x; rw[u][1] = a0.y; rw[u][2] = a1.x;
        rw[u][3] = a1.y; rw[u][4] = a2.x; rw[u][5] = a2.y;
      }
    }

    // acc init from global cb8 (32B stride -> aligned float4+float2, L1-resident)
    float acc[2][2][6];
    const float* cbp = cbg + WS_CB;
#pragma unroll
    for (int i = 0; i < 2; ++i)
#pragma unroll
      for (int j = 0; j < 2; ++j) {
        int pcell = (2 * r + i) * 12 + (2 * c + j);
        float4 ca  = *(const float4*)(cbp + pcell * 8);
        float2 ca2 = *(const float2*)(cbp + pcell * 8 + 4);
        acc[i][j][0] = b1[0] + ca.x;  acc[i][j][1] = b1[1] + ca.y;
        acc[i][j][2] = b1[2] + ca.z;  acc[i][j][3] = b1[3] + ca.w;
        acc[i][j][4] = b1[4] + ca2.x; acc[i][j][5] = b1[5] + ca2.y;
      }

    // dense ch0 (600 FMA); weights wave-uniform -> s_load (proven in R9-R11)
#pragma unroll
    for (int u = 0; u < 6; ++u) {
#pragma unroll
      for (int i = 0; i < 2; ++i) {
        if (u - i < 0 || u - i > 4) continue;   // folds at compile time
        const int ky = u - i;
#pragma unroll
        for (int j = 0; j < 2; ++j)
#pragma unroll
          for (int kx = 0; kx < 5; ++kx) {
            float xv = rw[u][j + kx];
#pragma unroll
            for (int o = 0; o < 6; ++o)
              acc[i][j][o] += xv * w1[o * 75 + ky * 5 + kx];   // uniform -> SGPR
          }
      }
    }

    // sparse piece taps (value==1 -> add weight); divergent -> w1L (o-contiguous)
#pragma unroll
    for (int e = 0; e < 8; ++e) {
      int pr = prA[e];
      if (pr < 0) continue;
      int pc = pcA[e];
      int chm = e >> 2;                       // 0 -> ch1, 1 -> ch2
      int dyb = pr + 2 - 2 * r;
      int dxb = pc + 2 - 2 * c;
      if (dyb < 0 || dyb > 5 || dxb < 0 || dxb > 5) continue;
#pragma unroll
      for (int i = 0; i < 2; ++i) {
        int dy = dyb - i;
        if ((unsigned)dy >= 5u) continue;
#pragma unroll
        for (int j = 0; j < 2; ++j) {
          int dx = dxb - j;
          if ((unsigned)dx >= 5u) continue;
          const float* wp = &w1L[(chm * 25 + dy * 5 + dx) * 6];
#pragma unroll
          for (int o = 0; o < 6; ++o)
            acc[i][j][o] += wp[o];
        }
      }
    }

    float* P1q = &scr[wv * SS2 + P1OFF];
#pragma unroll
    for (int o = 0; o < 6; ++o) {
      float v = fmaxf(acc[0][0][o], 0.f) + fmaxf(acc[0][1][o], 0.f)
              + fmaxf(acc[1][0][o], 0.f) + fmaxf(acc[1][1][o], 0.f);
      P1q[o * 61 + p] = 0.25f * v;
    }
  }
  __builtin_amdgcn_wave_barrier();

  // ------- conv2+relu (own sample): lane = (oc-group og, position p) -------
  if (lane < 48) {
    int og = lane / 12, p = lane - og * 12;   // og: oc group [4og,4og+4)
    int r = p >> 1, c = p & 1;
    const float* P1q = &scr[wv * SS2 + P1OFF];
    float4 bw = *(const float4*)(b2w + 4 * og);
    float a0 = bw.x, a1 = bw.y, a2 = bw.z, a3 = bw.w;
#pragma unroll
    for (int ic = 0; ic < 6; ++ic) {
      // stage a contiguous 29-float window: covers taps kr*6+kc (kr,kc<5)
      float vals[29];
      const float* pb = P1q + ic * 61 + r * 6 + c;
#pragma unroll
      for (int m = 0; m < 29; ++m) vals[m] = pb[m];
#pragma unroll
      for (int kr = 0; kr < 5; ++kr)
#pragma unroll
        for (int kc = 0; kc < 5; ++kc) {
          // one ds_read_b128 per tap; og offsets 0/16/32/48B -> banks 0/4/8/12
          float4 wt = *(const float4*)(&w2L[(ic * 25 + kr * 5 + kc) * 16 + 4 * og]);
          float xv = vals[kr * 6 + kc];
          a0 += xv * wt.x; a1 += xv * wt.y; a2 += xv * wt.z; a3 += xv * wt.w;
        }
    }
    float* C2q = &scr[wv * SS2];
    C2q[(4 * og + 0) * 12 + p] = fmaxf(a0, 0.f);
    C2q[(4 * og + 1) * 12 + p] = fmaxf(a1, 0.f);
    C2q[(4 * og + 2) * 12 + p] = fmaxf(a2, 0.f);
    C2q[(4 * og + 3) * 12 + p] = fmaxf(a3, 0.f);
  }
  __builtin_amdgcn_wave_barrier();

  // ---------------- per-wave tail (own sample) ----------------
  {
    const int q = wvu;
    float* S = &scr[q * SS2];

    // pool2: one b128 per lane
    if (lane < 48) {
      int o = lane / 3, pr = lane - o * 3;
      float4 v4 = *(const float4*)(S + o * 12 + 4 * pr);
      S[192 + lane] = 0.25f * (v4.x + v4.y + v4.z + v4.w);
    }
    __builtin_amdgcn_wave_barrier();

    // conv3 (fc over 48): per-lane row of w3 as 12 float4
    {
      int o = lane;
      const float4* w34 = (const float4*)(w3 + o * 48);
      const float4* S4  = (const float4*)(S + 192);
      float acc = b3[o];
#pragma unroll
      for (int m = 0; m < 12; ++m)
        acc += dot4(S4[m], w34[m]);
      S[240 + o] = fmaxf(acc, 0.f);
    }
    __builtin_amdgcn_wave_barrier();

    // lfc1: rows of wf1 as float4; split-k halves combined via shfl
    {
      int j = lane & 31, h = lane >> 5;
      const float4* wf4 = (const float4*)(wf1 + j * 64 + 32 * h);
      const float4* S4  = (const float4*)(S + 240 + 32 * h);
      float part = 0.f;
#pragma unroll
      for (int m = 0; m < 8; ++m)
        part += dot4(S4[m], wf4[m]);
      part += __shfl_xor(part, 32, 64);
      if (h == 0) {
        float acc = fmaxf(bf1[j] + part, 0.f);
        S[304 + j] = acc;
        out[(size_t)(bb + q) * 96 + 64 + j] = acc;
      }
    }
    __builtin_amdgcn_wave_barrier();

    {
      int j = lane & 31;
      if (lane < 32) {
        const float4* ip4 = (const float4*)(ipw + (size_t)(64 + j) * 32);
        const float4* S4  = (const float4*)(S + 304);
        float acc = ipb[64 + j];
#pragma unroll
        for (int m = 0; m < 8; ++m)
          acc += dot4(S4[m], ip4[m]);
        S[336 + j] = acc;
      } else {
        const int4* t4 = (const int4*)(t + (size_t)(bb + q) * 232);
        int4 ta = t4[0], tb = t4[1];
        const float4* fc4 = (const float4*)(fcw + j * 8);
        float4 wa = fc4[0], wb = fc4[1];
        float acc = fcb[j]
                  + (float)ta.x * wa.x + (float)ta.y * wa.y
                  + (float)ta.z * wa.z + (float)ta.w * wa.w
                  + (float)tb.x * wb.x + (float)tb.y * wb.y
                  + (float)tb.z * wb.z + (float)tb.w * wb.w;
        out[(size_t)(bb + q) * 96 + j] = fmaxf(acc, 0.f);
      }
    }
    __builtin_amdgcn_wave_barrier();

    if (lane < 32) {
      int j = lane;
      const float4* op4 = (const float4*)(opw + j * 32);
      const float4* S4  = (const float4*)(S + 336);
      float acc = opb[j];
#pragma unroll
      for (int m = 0; m < 8; ++m)
        acc += dot4(S4[m], op4[m]);
      out[(size_t)(bb + q) * 96 + 32 + j] = acc;
    }
  }
}

extern "C" void kernel_launch(void* const* d_in, const int* in_sizes, int n_in,
                              void* d_out, int out_size, void* d_ws, size_t ws_size,
                              hipStream_t stream) {
  const int*   t   = (const int*)d_in[0];
  const int*   pt  = (const int*)d_in[1];
  const float* w1  = (const float*)d_in[2];
  const float* b1  = (const float*)d_in[3];
  const float* w2  = (const float*)d_in[4];
  const float* b2w = (const float*)d_in[5];
  const float* w3  = (const float*)d_in[6];
  const float* b3  = (const float*)d_in[7];
  const float* wf1 = (const float*)d_in[8];
  const float* bf1 = (const float*)d_in[9];
  const float* fcw = (const float*)d_in[10];
  const float* fcb = (const float*)d_in[11];
  // d_in[12] = emb : dead (softmax over singleton axis == 1)
  const float* ipw = (const float*)d_in[13];
  const float* ipb = (const float*)d_in[14];
  const float* opw = (const float*)d_in[15];
  const float* opb = (const float*)d_in[16];

  float* out       = (float*)d_out;
  float* out_board = out + (size_t)BATCH * 96;
  float* cbg       = (float*)d_ws;     // WS_TOT floats (cb8 + w2T)

  hipLaunchKernelGGL(prep_kernel, dim3(18), dim3(256), 0, stream, w1, w2, cbg);
  hipLaunchKernelGGL(board_model_kernel, dim3(NBLK), dim3(256), 0, stream,
                     t, pt, w1, b1, w2, b2w, w3, b3, wf1, bf1, fcw, fcb,
                     ipw, ipb, opw, opb, cbg, out, out_board);
}

// Round 7
// 190.680 us; speedup vs baseline: 1.6839x; 1.0862x over previous
//
#include <hip/hip_runtime.h>
#include <cstddef>

// BoardModel: B=16384. out = [xf(32), a_mean(32), b2(32)] per sample, then board (3,22,12).
// MHA is degenerate (kv len 1 -> softmax==1): a_mean = out_proj(in_proj[64:96] @ b2 + b).
//
// R15 = R11 (the 102us best) with the code SIZE shrunk ~4x -- I$/front-end probe:
//   - R9-R14 post-mortems: dur invariant (~102us) under every data-path change
//     (staging width, weight path, barriers, layout); no data pipe >~55% busy.
//     Untested suspect: instruction fetch. R11 is ~24KB of straight-line unrolled
//     code vs a 32KB (CU-shared) L1I; every wave re-streams it.
//   - Change: roll the big unrolled regions, NOTHING else.
//       conv1 u-loop rolled (row re-staged per iter, R8 rolling-row form)
//       conv2 ic-loop rolled
//       sparse-tap e-loop rolled (pcs read from LDS per iter; no reg-array
//         runtime indexing anywhere -- rule-#20 checked per loop)
//       tail dot loops unroll(1)
//   - Same LDS layout/barriers/instruction counts as R11; only static code size
//     drops to ~6-8KB. s_loads re-issue per iteration (scalar pipe, hidden).
//   - Kept from R9-R11: LDS-only barriers (no vmcnt drain), ballot piece pick,
//     bitmask board channels, transposed w1L, int2 content loads, float4 tail.

#define BATCH 16384
#define SPB   4
#define NBLK  (BATCH / SPB)
#define RS    18
#define SBE_SZ 432          // 24 rows x 18
#define P1OFF  432          // P1: [o*61 + p], p<60 (bmi overlays this in Phase A)
#define PCSOFF 800          // 16 ints
#define SS2    816          // floats per sample; 816*4 % 16 == 0
                            // tail overlays SBE: C2 192 @0, P2 48 @192, C3 64 @240,
                            // B2 32 @304, V 32 @336.

// LDS-only block barrier: do NOT drain vmcnt (global stores keep flowing).
#define BSYNC() asm volatile("s_waitcnt lgkmcnt(0)\ns_barrier" ::: "memory")

static __device__ __forceinline__ float dot4(float4 a, float4 b) {
  return a.x * b.x + a.y * b.y + a.z * b.z + a.w * b.w;
}

// ---- C_border precompute: cb[p*6+o] = sum over window taps hitting border-one cells,
//      summed over all 3 input channels (border is 1.0 in every channel). ----
__global__ __launch_bounds__(256)
void cborder_kernel(const float* __restrict__ w1, float* __restrict__ cb)
{
  int i = blockIdx.x * 256 + threadIdx.x;
  if (i >= 1584) return;
  int p = i / 6, o = i - p * 6;
  int y0 = p / 12, x0 = p - y0 * 12;
  float acc = 0.f;
#pragma unroll
  for (int dy = 0; dy < 5; ++dy)
#pragma unroll
    for (int dx = 0; dx < 5; ++dx) {
      int pr = y0 + dy - 2, pc = x0 + dx - 2;
      if (pr >= 0 && pr < 22 && pc >= 0 && pc < 12 &&
          (pr == 21 || pc == 0 || pc == 11)) {
        int k = dy * 5 + dx;
        acc += w1[(o * 3 + 0) * 25 + k] + w1[(o * 3 + 1) * 25 + k]
             + w1[(o * 3 + 2) * 25 + k];
      }
    }
  cb[p * 6 + o] = acc;
}

__global__ __launch_bounds__(256, 4)
void board_model_kernel(const int* __restrict__ t,           // (B,232)
                        const int* __restrict__ piece_table, // (8,4,4,4)
                        const float* __restrict__ w1, const float* __restrict__ b1,
                        const float* __restrict__ w2, const float* __restrict__ b2w,
                        const float* __restrict__ w3, const float* __restrict__ b3,
                        const float* __restrict__ wf1, const float* __restrict__ bf1,
                        const float* __restrict__ fcw, const float* __restrict__ fcb,
                        const float* __restrict__ ipw, const float* __restrict__ ipb,
                        const float* __restrict__ opw, const float* __restrict__ opb,
                        const float* __restrict__ cbg,        // (264,6) border contrib
                        float* __restrict__ out,              // (B,96)
                        float* __restrict__ out_board)        // (B,3,22,12)
{
  __shared__ __align__(16) float scr[SPB * SS2];
  __shared__ float w1L[300];     // ch1/ch2 taps, transposed: [(chm*25 + tap)*6 + o]
  __shared__ float cbL[1440];    // conv cells rows 0..19 only (cb[p*6+o], p<240)

  const int tid  = threadIdx.x;
  const int lane = tid & 63;
  const int wv   = tid >> 6;          // wave id == sample slot
  const int bb   = blockIdx.x * SPB;

  for (int i = tid; i < 300; i += 256) {
    int o = i % 6, tt = i / 6, m = tt / 25, tp = tt - m * 25;
    w1L[i] = w1[(o * 3 + m + 1) * 25 + tp];
  }
  for (int i = tid; i < 1440; i += 256) cbL[i] = cbg[i];

  // ---------------- Phase A: per-wave board build + board output ----------------
  {
    float* W = &scr[wv * SS2];
    int*   pcs = (int*)&scr[wv * SS2 + PCSOFF];
    int*   bmi = (int*)&scr[wv * SS2 + P1OFF];   // 44 ints (Phase A only)
    const int* tr = t + (size_t)(bb + wv) * 232;

    float4* W4 = (float4*)W;
    for (int i = lane; i < 108; i += 64) W4[i] = float4{0.f, 0.f, 0.f, 0.f};
    if (lane < 44) bmi[lane] = 0;

    // content only (border handled via C_border): (r, b+1) -> SBE row r+2, col b+5
    // 210 ints at tr+22 (8B aligned); even pair offsets never cross a 10-wide row.
    {
      const int2* cp = (const int2*)(tr + 22);
      for (int v = lane; v < 105; v += 64) {
        int2 cv = cp[v];
        int i0 = v * 2;
        int r = i0 / 10, b = i0 - r * 10;
        W[(r + 2) * RS + b + 5] = (float)cv.x;
        W[(r + 2) * RS + b + 6] = (float)cv.y;
      }
    }

    // piece cells -> entry list; pieces always have exactly 4 cells -> ballot+ctz
    {
      const int* pt = piece_table + (tr[8] * 4 + tr[4]) * 16;
      int ptv = (lane < 16) ? pt[lane] : 0;
      unsigned long long bal = __ballot(ptv != 0);
      if (lane < 4) {
        unsigned x = (unsigned)bal & 0xffffu;
        for (int k = 0; k < lane; ++k) x &= x - 1;   // clear `lane` lowest set bits
        int sel = __builtin_ctz(x);
        int cy = sel >> 2, cx = sel & 3;
        int xx = cx + tr[1] - 2;
        int y  = cy + tr[2];
        int ny = y + tr[3];
        bool mask = (y >= 0) && (ny >= 0);
        bool xok  = (xx >= 0) && (xx < 10);
        bool v1 = mask && xok && (y < 21);
        bool v2 = mask && xok && (ny < 21);
        pcs[2 * lane + 0]       = v1 ? y  : -100;   // padded-board row
        pcs[2 * lane + 1]       = xx + 1;           // padded-board col
        pcs[2 * (lane + 4)]     = v2 ? ny : -100;
        pcs[2 * (lane + 4) + 1] = xx + 1;
        if (v1) atomicOr(&bmi[y],       1 << (xx + 1));
        if (v2) atomicOr(&bmi[22 + ny], 1 << (xx + 1));
      }
    }
    __builtin_amdgcn_wave_barrier();

    // board output: ch0 = border|content from SBE; ch1/2 = border | row bitmask
    float* ob = out_board + (size_t)(bb + wv) * 792;
    for (int v = lane; v < 198; v += 64) {
      int ch = v / 66, w = v - ch * 66;      // 66 float4 per channel
      int r = w / 3, c = (w - r * 3) * 4;    // c in {0,4,8}
      float val[4];
      if (ch == 0) {
#pragma unroll
        for (int d = 0; d < 4; ++d) {
          int cd = c + d;
          val[d] = (r == 21 || cd == 0 || cd == 11) ? 1.f
                 : W[(r + 2) * RS + cd + 4];
        }
      } else {
        int bits = bmi[(ch - 1) * 22 + r];
#pragma unroll
        for (int d = 0; d < 4; ++d) {
          int cd = c + d;
          val[d] = (r == 21 || cd == 0 || cd == 11 || ((bits >> cd) & 1)) ? 1.f : 0.f;
        }
      }
      *(float4*)(ob + v * 4) = float4{val[0], val[1], val[2], val[3]};
    }
  }
  BSYNC();   // guards w1L/cbL readiness (LDS only; board stores keep draining)

  // ------- Phase B: fused conv1+relu+pool1; wave = sample, lane = position <60 -------
  if (lane < 60) {
    int p = lane;
    int r = p / 6, c = p - r * 6;
    const float* Wq  = &scr[wv * SS2];
    const int*   pcs = (const int*)&scr[wv * SS2 + PCSOFF];

    float acc[2][2][6];
#pragma unroll
    for (int i = 0; i < 2; ++i)
#pragma unroll
      for (int j = 0; j < 2; ++j) {
        int pcell = (2 * r + i) * 12 + (2 * c + j);
#pragma unroll
        for (int o = 0; o < 6; ++o)
          acc[i][j][o] = b1[o] + cbL[pcell * 6 + o];
      }

    // dense ch0 (600 FMA); u-loop ROLLED (I$ probe): one input row staged per iter,
    // weights wave-uniform -> s_load inside loop (scalar pipe, hidden under FMAs)
#pragma unroll 1
    for (int u = 0; u < 6; ++u) {
      const float* base = Wq + (2 * r + u) * RS + (2 * c + 2);
      float2 a0 = *(const float2*)(base);
      float2 a1 = *(const float2*)(base + 2);
      float2 a2 = *(const float2*)(base + 4);
      float rv[6] = {a0.x, a0.y, a1.x, a1.y, a2.x, a2.y};
#pragma unroll
      for (int i = 0; i < 2; ++i) {
        int ky = u - i;
        if (ky < 0 || ky > 4) continue;     // runtime branch (u is a loop var now)
#pragma unroll
        for (int j = 0; j < 2; ++j)
#pragma unroll
          for (int kx = 0; kx < 5; ++kx) {
            float xv = rv[j + kx];
#pragma unroll
            for (int o = 0; o < 6; ++o)
              acc[i][j][o] += xv * w1[o * 75 + ky * 5 + kx];   // uniform -> SGPR
          }
      }
    }

    // sparse piece taps; e-loop ROLLED (pcs read per iter from LDS -> no reg-array
    // runtime indexing); divergent weights from w1L (o-contiguous)
#pragma unroll 1
    for (int e = 0; e < 8; ++e) {
      int pr = pcs[2 * e];
      if (pr < 0) continue;
      int pc = pcs[2 * e + 1];
      int chm = e >> 2;                       // 0 -> ch1, 1 -> ch2
      int dyb = pr + 2 - 2 * r;
      int dxb = pc + 2 - 2 * c;
      if (dyb < 0 || dyb > 5 || dxb < 0 || dxb > 5) continue;
#pragma unroll
      for (int i = 0; i < 2; ++i) {
        int dy = dyb - i;
        if ((unsigned)dy >= 5u) continue;
#pragma unroll
        for (int j = 0; j < 2; ++j) {
          int dx = dxb - j;
          if ((unsigned)dx >= 5u) continue;
          const float* wp = &w1L[(chm * 25 + dy * 5 + dx) * 6];
#pragma unroll
          for (int o = 0; o < 6; ++o)
            acc[i][j][o] += wp[o];
        }
      }
    }

    float* P1q = &scr[wv * SS2 + P1OFF];
#pragma unroll
    for (int o = 0; o < 6; ++o) {
      float v = fmaxf(acc[0][0][o], 0.f) + fmaxf(acc[0][1][o], 0.f)
              + fmaxf(acc[1][0][o], 0.f) + fmaxf(acc[1][1][o], 0.f);
      P1q[o * 61 + p] = 0.25f * v;
    }
  }
  BSYNC();   // P1 ready across waves (LDS only)

  // ---------------- conv2+relu: wave wvu -> out-channels [4wvu,4wvu+4), all samples ----
  const int wvu = __builtin_amdgcn_readfirstlane(wv);

  if (lane < 48) {
    int q = lane / 12, p = lane - q * 12;
    int r = p >> 1, c = p & 1;
    const float* P1q = &scr[q * SS2 + P1OFF];
    float a4[4];
#pragma unroll
    for (int oo = 0; oo < 4; ++oo) a4[oo] = b2w[4 * wvu + oo];

    // ic-loop ROLLED (I$ probe); weights re-s_loaded per iter (scalar pipe)
#pragma unroll 1
    for (int ic = 0; ic < 6; ++ic) {
      // stage a contiguous 29-float window: covers taps kr*6+kc (kr,kc<5)
      float vals[29];
      const float* pb = P1q + ic * 61 + r * 6 + c;
#pragma unroll
      for (int m = 0; m < 29; ++m) vals[m] = pb[m];
      const float* wp = w2 + (size_t)(24 * wvu + ic) * 25;   // + oo*150 per channel
#pragma unroll
      for (int kr = 0; kr < 5; ++kr)
#pragma unroll
        for (int kc = 0; kc < 5; ++kc) {
          float xv = vals[kr * 6 + kc];
          a4[0] += xv * wp[kr * 5 + kc];
          a4[1] += xv * wp[150 + kr * 5 + kc];
          a4[2] += xv * wp[300 + kr * 5 + kc];
          a4[3] += xv * wp[450 + kr * 5 + kc];
        }
    }
    float* C2q = &scr[q * SS2];
#pragma unroll
    for (int oo = 0; oo < 4; ++oo)
      C2q[(4 * wvu + oo) * 12 + p] = fmaxf(a4[oo], 0.f);
  }
  BSYNC();   // C2 ready (LDS only)

  // ---------------- per-wave tail: wave q owns sample q ----------------
  {
    const int q = wvu;
    float* S = &scr[q * SS2];

    // pool2: one b128 per lane
    if (lane < 48) {
      int o = lane / 3, pr = lane - o * 3;
      float4 v4 = *(const float4*)(S + o * 12 + 4 * pr);
      S[192 + lane] = 0.25f * (v4.x + v4.y + v4.z + v4.w);
    }
    __builtin_amdgcn_wave_barrier();

    // conv3 (fc over 48): per-lane row of w3 as 12 float4 (rolled)
    {
      int o = lane;
      const float4* w34 = (const float4*)(w3 + o * 48);
      const float4* S4  = (const float4*)(S + 192);
      float acc = b3[o];
#pragma unroll 1
      for (int m = 0; m < 12; ++m)
        acc += dot4(S4[m], w34[m]);
      S[240 + o] = fmaxf(acc, 0.f);
    }
    __builtin_amdgcn_wave_barrier();

    // lfc1: rows of wf1 as float4; split-k halves combined via shfl (rolled)
    {
      int j = lane & 31, h = lane >> 5;
      const float4* wf4 = (const float4*)(wf1 + j * 64 + 32 * h);
      const float4* S4  = (const float4*)(S + 240 + 32 * h);
      float part = 0.f;
#pragma unroll 1
      for (int m = 0; m < 8; ++m)
        part += dot4(S4[m], wf4[m]);
      part += __shfl_xor(part, 32, 64);
      if (h == 0) {
        float acc = fmaxf(bf1[j] + part, 0.f);
        S[304 + j] = acc;
        out[(size_t)(bb + q) * 96 + 64 + j] = acc;
      }
    }
    __builtin_amdgcn_wave_barrier();

    {
      int j = lane & 31;
      if (lane < 32) {
        // v-proj: rows 64..95 of ipw as float4 (rolled)
        const float4* ip4 = (const float4*)(ipw + (size_t)(64 + j) * 32);
        const float4* S4  = (const float4*)(S + 304);
        float acc = ipb[64 + j];
#pragma unroll 1
        for (int m = 0; m < 8; ++m)
          acc += dot4(S4[m], ip4[m]);
        S[336 + j] = acc;
      } else {
        // xf: t row is 928B (16B aligned); fcw row is 32B
        const int4* t4 = (const int4*)(t + (size_t)(bb + q) * 232);
        int4 ta = t4[0], tb = t4[1];
        const float4* fc4 = (const float4*)(fcw + j * 8);
        float4 wa = fc4[0], wb = fc4[1];
        float acc = fcb[j]
                  + (float)ta.x * wa.x + (float)ta.y * wa.y
                  + (float)ta.z * wa.z + (float)ta.w * wa.w
                  + (float)tb.x * wb.x + (float)tb.y * wb.y
                  + (float)tb.z * wb.z + (float)tb.w * wb.w;
        out[(size_t)(bb + q) * 96 + j] = fmaxf(acc, 0.f);
      }
    }
    __builtin_amdgcn_wave_barrier();

    if (lane < 32) {
      int j = lane;
      const float4* op4 = (const float4*)(opw + j * 32);
      const float4* S4  = (const float4*)(S + 336);
      float acc = opb[j];
#pragma unroll 1
      for (int m = 0; m < 8; ++m)
        acc += dot4(S4[m], op4[m]);
      out[(size_t)(bb + q) * 96 + 32 + j] = acc;
    }
  }
}

extern "C" void kernel_launch(void* const* d_in, const int* in_sizes, int n_in,
                              void* d_out, int out_size, void* d_ws, size_t ws_size,
                              hipStream_t stream) {
  const int*   t   = (const int*)d_in[0];
  const int*   pt  = (const int*)d_in[1];
  const float* w1  = (const float*)d_in[2];
  const float* b1  = (const float*)d_in[3];
  const float* w2  = (const float*)d_in[4];
  const float* b2w = (const float*)d_in[5];
  const float* w3  = (const float*)d_in[6];
  const float* b3  = (const float*)d_in[7];
  const float* wf1 = (const float*)d_in[8];
  const float* bf1 = (const float*)d_in[9];
  const float* fcw = (const float*)d_in[10];
  const float* fcb = (const float*)d_in[11];
  // d_in[12] = emb : dead (softmax over singleton axis == 1)
  const float* ipw = (const float*)d_in[13];
  const float* ipb = (const float*)d_in[14];
  const float* opw = (const float*)d_in[15];
  const float* opb = (const float*)d_in[16];

  float* out       = (float*)d_out;
  float* out_board = out + (size_t)BATCH * 96;
  float* cbg       = (float*)d_ws;     // 1584 floats

  hipLaunchKernelGGL(cborder_kernel, dim3(7), dim3(256), 0, stream, w1, cbg);
  hipLaunchKernelGGL(board_model_kernel, dim3(NBLK), dim3(256), 0, stream,
                     t, pt, w1, b1, w2, b2w, w3, b3, wf1, bf1, fcw, fcb,
                     ipw, ipb, opw, opb, cbg, out, out_board);
}

// Round 8
// 182.982 us; speedup vs baseline: 1.7548x; 1.0421x over previous
//
#include <hip/hip_runtime.h>
#include <cstddef>

// BoardModel: B=16384. out = [xf(32), a_mean(32), b2(32)] per sample, then board (3,22,12).
// MHA is degenerate (kv len 1 -> softmax==1): a_mean = out_proj(in_proj[64:96] @ b2 + b).
//
// R16 = R15 (96us, code-size win confirmed) + two more cuts on the same gradient:
//   - conv2 DOUBLE-rolled (ic x kr, 30 iters, ~30-inst body): kills the 29-float
//     vals[] staging entirely (174 -> 150 b32 reads/wave), shrinks conv2 code ~2x.
//     Reads go straight from LDS per iter -- no reg-array runtime indexing (rule #20).
//   - cbL removed from LDS: conv1 acc init reads padded global cb8[pcell*8+o] as
//     aligned float4+float2 (8 indep VMEM loads, table L1/L2-resident, hidden under
//     window ds_reads).  Removes 1440-float per-block staging, 24 scalar LDS
//     reads/wave, 5.8KB LDS (block 20480 -> ~14.6KB).
//   - Kept from R15: rolled conv1 u-loop, rolled sparse-tap e-loop, rolled tail
//     dots, LDS-only barriers, ballot piece pick, bitmask board channels,
//     transposed w1L, int2 content loads, float4 tail.

#define BATCH 16384
#define SPB   4
#define NBLK  (BATCH / SPB)
#define RS    18
#define P1OFF  432          // P1: [o*61 + p], p<60 (bmi overlays this in Phase A)
#define PCSOFF 800          // 16 ints
#define SS2    816          // floats per sample; 816*4 % 16 == 0
                            // tail overlays SBE: C2 192 @0, P2 48 @192, C3 64 @240,
                            // B2 32 @304, V 32 @336.

// LDS-only block barrier: do NOT drain vmcnt (global stores keep flowing).
#define BSYNC() asm volatile("s_waitcnt lgkmcnt(0)\ns_barrier" ::: "memory")

static __device__ __forceinline__ float dot4(float4 a, float4 b) {
  return a.x * b.x + a.y * b.y + a.z * b.z + a.w * b.w;
}

// ---- cb8 precompute: cb8[p*8+o] = sum over window taps hitting border-one cells,
//      summed over all 3 input channels (border is 1.0 in every channel). ----
__global__ __launch_bounds__(256)
void cb8_kernel(const float* __restrict__ w1, float* __restrict__ cb8)
{
  int i = blockIdx.x * 256 + threadIdx.x;
  if (i >= 2112) return;
  int p = i >> 3, o = i & 7;
  float acc = 0.f;
  if (o < 6) {
    int y0 = p / 12, x0 = p - y0 * 12;
#pragma unroll
    for (int dy = 0; dy < 5; ++dy)
#pragma unroll
      for (int dx = 0; dx < 5; ++dx) {
        int pr = y0 + dy - 2, pc = x0 + dx - 2;
        if (pr >= 0 && pr < 22 && pc >= 0 && pc < 12 &&
            (pr == 21 || pc == 0 || pc == 11)) {
          int k = dy * 5 + dx;
          acc += w1[(o * 3 + 0) * 25 + k] + w1[(o * 3 + 1) * 25 + k]
               + w1[(o * 3 + 2) * 25 + k];
        }
      }
  }
  cb8[i] = acc;
}

__global__ __launch_bounds__(256, 4)
void board_model_kernel(const int* __restrict__ t,           // (B,232)
                        const int* __restrict__ piece_table, // (8,4,4,4)
                        const float* __restrict__ w1, const float* __restrict__ b1,
                        const float* __restrict__ w2, const float* __restrict__ b2w,
                        const float* __restrict__ w3, const float* __restrict__ b3,
                        const float* __restrict__ wf1, const float* __restrict__ bf1,
                        const float* __restrict__ fcw, const float* __restrict__ fcb,
                        const float* __restrict__ ipw, const float* __restrict__ ipb,
                        const float* __restrict__ opw, const float* __restrict__ opb,
                        const float* __restrict__ cbg,        // cb8: (264,8) border contrib
                        float* __restrict__ out,              // (B,96)
                        float* __restrict__ out_board)        // (B,3,22,12)
{
  __shared__ __align__(16) float scr[SPB * SS2];
  __shared__ float w1L[300];     // ch1/ch2 taps, transposed: [(chm*25 + tap)*6 + o]

  const int tid  = threadIdx.x;
  const int lane = tid & 63;
  const int wv   = tid >> 6;          // wave id == sample slot
  const int bb   = blockIdx.x * SPB;

  for (int i = tid; i < 300; i += 256) {
    int o = i % 6, tt = i / 6, m = tt / 25, tp = tt - m * 25;
    w1L[i] = w1[(o * 3 + m + 1) * 25 + tp];
  }

  // ---------------- Phase A: per-wave board build + board output ----------------
  {
    float* W = &scr[wv * SS2];
    int*   pcs = (int*)&scr[wv * SS2 + PCSOFF];
    int*   bmi = (int*)&scr[wv * SS2 + P1OFF];   // 44 ints (Phase A only)
    const int* tr = t + (size_t)(bb + wv) * 232;

    float4* W4 = (float4*)W;
    for (int i = lane; i < 108; i += 64) W4[i] = float4{0.f, 0.f, 0.f, 0.f};
    if (lane < 44) bmi[lane] = 0;

    // content only (border handled via cb8): (r, b+1) -> SBE row r+2, col b+5
    // 210 ints at tr+22 (8B aligned); even pair offsets never cross a 10-wide row.
    {
      const int2* cp = (const int2*)(tr + 22);
      for (int v = lane; v < 105; v += 64) {
        int2 cv = cp[v];
        int i0 = v * 2;
        int r = i0 / 10, b = i0 - r * 10;
        W[(r + 2) * RS + b + 5] = (float)cv.x;
        W[(r + 2) * RS + b + 6] = (float)cv.y;
      }
    }

    // piece cells -> entry list; pieces always have exactly 4 cells -> ballot+ctz
    {
      const int* pt = piece_table + (tr[8] * 4 + tr[4]) * 16;
      int ptv = (lane < 16) ? pt[lane] : 0;
      unsigned long long bal = __ballot(ptv != 0);
      if (lane < 4) {
        unsigned x = (unsigned)bal & 0xffffu;
        for (int k = 0; k < lane; ++k) x &= x - 1;   // clear `lane` lowest set bits
        int sel = __builtin_ctz(x);
        int cy = sel >> 2, cx = sel & 3;
        int xx = cx + tr[1] - 2;
        int y  = cy + tr[2];
        int ny = y + tr[3];
        bool mask = (y >= 0) && (ny >= 0);
        bool xok  = (xx >= 0) && (xx < 10);
        bool v1 = mask && xok && (y < 21);
        bool v2 = mask && xok && (ny < 21);
        pcs[2 * lane + 0]       = v1 ? y  : -100;   // padded-board row
        pcs[2 * lane + 1]       = xx + 1;           // padded-board col
        pcs[2 * (lane + 4)]     = v2 ? ny : -100;
        pcs[2 * (lane + 4) + 1] = xx + 1;
        if (v1) atomicOr(&bmi[y],       1 << (xx + 1));
        if (v2) atomicOr(&bmi[22 + ny], 1 << (xx + 1));
      }
    }
    __builtin_amdgcn_wave_barrier();

    // board output: ch0 = border|content from SBE; ch1/2 = border | row bitmask
    float* ob = out_board + (size_t)(bb + wv) * 792;
    for (int v = lane; v < 198; v += 64) {
      int ch = v / 66, w = v - ch * 66;      // 66 float4 per channel
      int r = w / 3, c = (w - r * 3) * 4;    // c in {0,4,8}
      float val[4];
      if (ch == 0) {
#pragma unroll
        for (int d = 0; d < 4; ++d) {
          int cd = c + d;
          val[d] = (r == 21 || cd == 0 || cd == 11) ? 1.f
                 : W[(r + 2) * RS + cd + 4];
        }
      } else {
        int bits = bmi[(ch - 1) * 22 + r];
#pragma unroll
        for (int d = 0; d < 4; ++d) {
          int cd = c + d;
          val[d] = (r == 21 || cd == 0 || cd == 11 || ((bits >> cd) & 1)) ? 1.f : 0.f;
        }
      }
      *(float4*)(ob + v * 4) = float4{val[0], val[1], val[2], val[3]};
    }
  }
  BSYNC();   // guards w1L readiness (LDS only; board stores keep draining)

  // ------- Phase B: fused conv1+relu+pool1; wave = sample, lane = position <60 -------
  if (lane < 60) {
    int p = lane;
    int r = p / 6, c = p - r * 6;
    const float* Wq  = &scr[wv * SS2];
    const int*   pcs = (const int*)&scr[wv * SS2 + PCSOFF];

    // acc init from global cb8 (32B stride -> aligned float4+float2, cache-resident,
    // 8 independent VMEM loads hidden under the first window ds_reads)
    float acc[2][2][6];
#pragma unroll
    for (int i = 0; i < 2; ++i)
#pragma unroll
      for (int j = 0; j < 2; ++j) {
        int pcell = (2 * r + i) * 12 + (2 * c + j);
        float4 ca  = *(const float4*)(cbg + pcell * 8);
        float2 ca2 = *(const float2*)(cbg + pcell * 8 + 4);
        acc[i][j][0] = b1[0] + ca.x;  acc[i][j][1] = b1[1] + ca.y;
        acc[i][j][2] = b1[2] + ca.z;  acc[i][j][3] = b1[3] + ca.w;
        acc[i][j][4] = b1[4] + ca2.x; acc[i][j][5] = b1[5] + ca2.y;
      }

    // dense ch0 (600 FMA); u-loop ROLLED: one input row staged per iter,
    // weights wave-uniform -> s_load inside loop (scalar pipe)
#pragma unroll 1
    for (int u = 0; u < 6; ++u) {
      const float* base = Wq + (2 * r + u) * RS + (2 * c + 2);
      float2 a0 = *(const float2*)(base);
      float2 a1 = *(const float2*)(base + 2);
      float2 a2 = *(const float2*)(base + 4);
      float rv[6] = {a0.x, a0.y, a1.x, a1.y, a2.x, a2.y};
#pragma unroll
      for (int i = 0; i < 2; ++i) {
        int ky = u - i;
        if (ky < 0 || ky > 4) continue;     // runtime branch (u is a loop var)
#pragma unroll
        for (int j = 0; j < 2; ++j)
#pragma unroll
          for (int kx = 0; kx < 5; ++kx) {
            float xv = rv[j + kx];
#pragma unroll
            for (int o = 0; o < 6; ++o)
              acc[i][j][o] += xv * w1[o * 75 + ky * 5 + kx];   // uniform -> SGPR
          }
      }
    }

    // sparse piece taps; e-loop ROLLED (pcs read per iter from LDS)
#pragma unroll 1
    for (int e = 0; e < 8; ++e) {
      int pr = pcs[2 * e];
      if (pr < 0) continue;
      int pc = pcs[2 * e + 1];
      int chm = e >> 2;                       // 0 -> ch1, 1 -> ch2
      int dyb = pr + 2 - 2 * r;
      int dxb = pc + 2 - 2 * c;
      if (dyb < 0 || dyb > 5 || dxb < 0 || dxb > 5) continue;
#pragma unroll
      for (int i = 0; i < 2; ++i) {
        int dy = dyb - i;
        if ((unsigned)dy >= 5u) continue;
#pragma unroll
        for (int j = 0; j < 2; ++j) {
          int dx = dxb - j;
          if ((unsigned)dx >= 5u) continue;
          const float* wp = &w1L[(chm * 25 + dy * 5 + dx) * 6];
#pragma unroll
          for (int o = 0; o < 6; ++o)
            acc[i][j][o] += wp[o];
        }
      }
    }

    float* P1q = &scr[wv * SS2 + P1OFF];
#pragma unroll
    for (int o = 0; o < 6; ++o) {
      float v = fmaxf(acc[0][0][o], 0.f) + fmaxf(acc[0][1][o], 0.f)
              + fmaxf(acc[1][0][o], 0.f) + fmaxf(acc[1][1][o], 0.f);
      P1q[o * 61 + p] = 0.25f * v;
    }
  }
  BSYNC();   // P1 ready across waves (LDS only)

  // ---------------- conv2+relu: wave wvu -> out-channels [4wvu,4wvu+4), all samples ----
  const int wvu = __builtin_amdgcn_readfirstlane(wv);

  if (lane < 48) {
    int q = lane / 12, p = lane - q * 12;
    int r = p >> 1, c = p & 1;
    const float* P1q = &scr[q * SS2 + P1OFF];
    float a4[4];
#pragma unroll
    for (int oo = 0; oo < 4; ++oo) a4[oo] = b2w[4 * wvu + oo];

    // DOUBLE-rolled (ic x kr): ~30-inst body, reads direct from LDS (no vals[])
#pragma unroll 1
    for (int ic = 0; ic < 6; ++ic) {
      const float* pb = P1q + ic * 61 + r * 6 + c;
      const float* wp = w2 + (size_t)(4 * wvu) * 150 + ic * 25;  // + oo*150
#pragma unroll 1
      for (int kr = 0; kr < 5; ++kr) {
        float x0 = pb[kr * 6 + 0];
        float x1 = pb[kr * 6 + 1];
        float x2 = pb[kr * 6 + 2];
        float x3 = pb[kr * 6 + 3];
        float x4 = pb[kr * 6 + 4];
        const float* wr = wp + kr * 5;
#pragma unroll
        for (int oo = 0; oo < 4; ++oo) {
          const float* w = wr + oo * 150;
          a4[oo] += x0 * w[0] + x1 * w[1] + x2 * w[2] + x3 * w[3] + x4 * w[4];
        }
      }
    }
    float* C2q = &scr[q * SS2];
#pragma unroll
    for (int oo = 0; oo < 4; ++oo)
      C2q[(4 * wvu + oo) * 12 + p] = fmaxf(a4[oo], 0.f);
  }
  BSYNC();   // C2 ready (LDS only)

  // ---------------- per-wave tail: wave q owns sample q ----------------
  {
    const int q = wvu;
    float* S = &scr[q * SS2];

    // pool2: one b128 per lane
    if (lane < 48) {
      int o = lane / 3, pr = lane - o * 3;
      float4 v4 = *(const float4*)(S + o * 12 + 4 * pr);
      S[192 + lane] = 0.25f * (v4.x + v4.y + v4.z + v4.w);
    }
    __builtin_amdgcn_wave_barrier();

    // conv3 (fc over 48): per-lane row of w3 as 12 float4 (rolled)
    {
      int o = lane;
      const float4* w34 = (const float4*)(w3 + o * 48);
      const float4* S4  = (const float4*)(S + 192);
      float acc = b3[o];
#pragma unroll 1
      for (int m = 0; m < 12; ++m)
        acc += dot4(S4[m], w34[m]);
      S[240 + o] = fmaxf(acc, 0.f);
    }
    __builtin_amdgcn_wave_barrier();

    // lfc1: rows of wf1 as float4; split-k halves combined via shfl (rolled)
    {
      int j = lane & 31, h = lane >> 5;
      const float4* wf4 = (const float4*)(wf1 + j * 64 + 32 * h);
      const float4* S4  = (const float4*)(S + 240 + 32 * h);
      float part = 0.f;
#pragma unroll 1
      for (int m = 0; m < 8; ++m)
        part += dot4(S4[m], wf4[m]);
      part += __shfl_xor(part, 32, 64);
      if (h == 0) {
        float acc = fmaxf(bf1[j] + part, 0.f);
        S[304 + j] = acc;
        out[(size_t)(bb + q) * 96 + 64 + j] = acc;
      }
    }
    __builtin_amdgcn_wave_barrier();

    {
      int j = lane & 31;
      if (lane < 32) {
        // v-proj: rows 64..95 of ipw as float4 (rolled)
        const float4* ip4 = (const float4*)(ipw + (size_t)(64 + j) * 32);
        const float4* S4  = (const float4*)(S + 304);
        float acc = ipb[64 + j];
#pragma unroll 1
        for (int m = 0; m < 8; ++m)
          acc += dot4(S4[m], ip4[m]);
        S[336 + j] = acc;
      } else {
        // xf: t row is 928B (16B aligned); fcw row is 32B
        const int4* t4 = (const int4*)(t + (size_t)(bb + q) * 232);
        int4 ta = t4[0], tb = t4[1];
        const float4* fc4 = (const float4*)(fcw + j * 8);
        float4 wa = fc4[0], wb = fc4[1];
        float acc = fcb[j]
                  + (float)ta.x * wa.x + (float)ta.y * wa.y
                  + (float)ta.z * wa.z + (float)ta.w * wa.w
                  + (float)tb.x * wb.x + (float)tb.y * wb.y
                  + (float)tb.z * wb.z + (float)tb.w * wb.w;
        out[(size_t)(bb + q) * 96 + j] = fmaxf(acc, 0.f);
      }
    }
    __builtin_amdgcn_wave_barrier();

    if (lane < 32) {
      int j = lane;
      const float4* op4 = (const float4*)(opw + j * 32);
      const float4* S4  = (const float4*)(S + 336);
      float acc = opb[j];
#pragma unroll 1
      for (int m = 0; m < 8; ++m)
        acc += dot4(S4[m], op4[m]);
      out[(size_t)(bb + q) * 96 + 32 + j] = acc;
    }
  }
}

extern "C" void kernel_launch(void* const* d_in, const int* in_sizes, int n_in,
                              void* d_out, int out_size, void* d_ws, size_t ws_size,
                              hipStream_t stream) {
  const int*   t   = (const int*)d_in[0];
  const int*   pt  = (const int*)d_in[1];
  const float* w1  = (const float*)d_in[2];
  const float* b1  = (const float*)d_in[3];
  const float* w2  = (const float*)d_in[4];
  const float* b2w = (const float*)d_in[5];
  const float* w3  = (const float*)d_in[6];
  const float* b3  = (const float*)d_in[7];
  const float* wf1 = (const float*)d_in[8];
  const float* bf1 = (const float*)d_in[9];
  const float* fcw = (const float*)d_in[10];
  const float* fcb = (const float*)d_in[11];
  // d_in[12] = emb : dead (softmax over singleton axis == 1)
  const float* ipw = (const float*)d_in[13];
  const float* ipb = (const float*)d_in[14];
  const float* opw = (const float*)d_in[15];
  const float* opb = (const float*)d_in[16];

  float* out       = (float*)d_out;
  float* out_board = out + (size_t)BATCH * 96;
  float* cbg       = (float*)d_ws;     // 2112 floats: cb8[p*8+o]

  hipLaunchKernelGGL(cb8_kernel, dim3(9), dim3(256), 0, stream, w1, cbg);
  hipLaunchKernelGGL(board_model_kernel, dim3(NBLK), dim3(256), 0, stream,
                     t, pt, w1, b1, w2, b2w, w3, b3, wf1, bf1, fcw, fcb,
                     ipw, ipb, opw, opb, cbg, out, out_board);
}